// Round 5
// baseline (68.204 us; speedup 1.0000x reference)
//
#include <hip/hip_runtime.h>

#define N        8192   // 8*32*32  (DEPTH=8 x, LENGTH=32 y, WIDTH=32 z)
#define NCLS     8
#define RPW      4                       // rows per wave
#define WPB      4                       // waves per block
#define ROWS_PB  (RPW * WPB)             // 16 rows per block
#define GRID     (N / ROWS_PB)           // 512 blocks

// One WAVE handles RPW=4 rows serially. Lanes cover the exact significant
// neighborhood of each row: y in [yi-3,yi+3] (7) x z in [zi-4,zi+4] (9) =
// 63 lanes, x-loop of 7 (clamp-shifted windows always inside the volume).
// Dropped terms have weight <= exp(-16) ~ 1e-7; computed terms are exact
// (validated R2-R4: absmax 0.0).
//
// Key change vs R4: per-row 9 partials (wp[8], rs) are folded into 16
// PRE-WEIGHTED register accumulators (u_t += P[i,t]*wp_t, d_t += P[i,t]*rs)
// so the expensive 16-value wave shuffle reduction happens ONCE per 4 rows
// instead of a 9-value reduction per row. No atomics, no fences, no
// zero-init of d_ws (every partial byte is overwritten).
__global__ __launch_bounds__(256) void sncut_rows(const float* __restrict__ f,
                                                  const float* __restrict__ P,
                                                  float* __restrict__ partials)
{
    const int tid  = threadIdx.x;
    const int lane = tid & 63;
    const int wave = tid >> 6;

    const int oy = lane / 9, oz = lane - oy * 9;   // 7 x 9 = 63 active lanes
    const bool active = (lane < 63);

    float u0=0.f,u1=0.f,u2=0.f,u3=0.f,u4=0.f,u5=0.f,u6=0.f,u7=0.f;  // num partials
    float d0=0.f,d1=0.f,d2=0.f,d3=0.f,d4=0.f,d5=0.f,d6=0.f,d7=0.f;  // den partials

    const int ibase = blockIdx.x * ROWS_PB + wave * RPW;

    for (int r = 0; r < RPW; ++r) {
        const int i  = ibase + r;
        const int zi = i & 31, yi = (i >> 5) & 31, xi = i >> 10;
        const float fi = f[i];

        float wp0=0.f,wp1=0.f,wp2=0.f,wp3=0.f,wp4=0.f,wp5=0.f,wp6=0.f,wp7=0.f;
        float rs = 0.f;

        if (active) {
            int y0 = yi - 3; y0 = y0 < 0 ? 0 : (y0 > 25 ? 25 : y0);
            int z0 = zi - 4; z0 = z0 < 0 ? 0 : (z0 > 23 ? 23 : z0);
            int x0 = xi - 3; x0 = x0 < 0 ? 0 : (x0 > 1 ? 1 : x0);

            const int yj = y0 + oy, zj = z0 + oz;
            const int dy = yi - yj, dz = zi - zj;
            const float base = (float)(dy * dy + dz * dz);
            const int jcol = (yj << 5) + zj;

            #pragma unroll
            for (int k = 0; k < 7; ++k) {
                const int xj = x0 + k;
                const int dx = xi - xj;
                const int j  = (xj << 10) + jcol;
                const float df  = fi - f[j];
                const float arg = df * df * (1.0f / 9.0f) + (base + (float)(dx * dx));
                const float w   = __expf(-arg);
                const float4 p0 = *reinterpret_cast<const float4*>(P + (size_t)j * NCLS);
                const float4 p1 = *reinterpret_cast<const float4*>(P + (size_t)j * NCLS + 4);
                wp0 += w * p0.x; wp1 += w * p0.y; wp2 += w * p0.z; wp3 += w * p0.w;
                wp4 += w * p1.x; wp5 += w * p1.y; wp6 += w * p1.z; wp7 += w * p1.w;
                rs  += w;
            }
        }

        // fold this row into pre-weighted accumulators (P[i,*] is wave-uniform)
        const float4 pi0 = *reinterpret_cast<const float4*>(P + (size_t)i * NCLS);
        const float4 pi1 = *reinterpret_cast<const float4*>(P + (size_t)i * NCLS + 4);
        u0 += pi0.x * wp0; u1 += pi0.y * wp1; u2 += pi0.z * wp2; u3 += pi0.w * wp3;
        u4 += pi1.x * wp4; u5 += pi1.y * wp5; u6 += pi1.z * wp6; u7 += pi1.w * wp7;
        d0 += pi0.x * rs;  d1 += pi0.y * rs;  d2 += pi0.z * rs;  d3 += pi0.w * rs;
        d4 += pi1.x * rs;  d5 += pi1.y * rs;  d6 += pi1.z * rs;  d7 += pi1.w * rs;
    }

    // ---- ONE 16-value wave reduction per 4 rows (result lands in lane 0)
    float vals[16] = {u0,u1,u2,u3,u4,u5,u6,u7,d0,d1,d2,d3,d4,d5,d6,d7};
    #pragma unroll
    for (int v = 0; v < 16; ++v) {
        float x = vals[v];
        #pragma unroll
        for (int off = 32; off > 0; off >>= 1)
            x += __shfl_down(x, off, 64);
        vals[v] = x;
    }

    __shared__ float sh[WPB][16];
    if (lane == 0) {
        #pragma unroll
        for (int v = 0; v < 16; ++v) sh[wave][v] = vals[v];
    }
    __syncthreads();
    if (tid < 16)
        partials[(size_t)blockIdx.x * 16 + tid] =
            sh[0][tid] + sh[1][tid] + sh[2][tid] + sh[3][tid];
}

// Fold 512 x 16 partials -> 16 sums -> scalar loss. 512 threads: thread
// (g = tid>>4 in [0,32), e = tid&15) sums 16 strided entries (independent
// loads, latency hidden), LDS combine across the 32 groups.
__global__ __launch_bounds__(512) void sncut_final(const float* __restrict__ partials,
                                                   float* __restrict__ out)
{
    const int tid = threadIdx.x;
    const int e = tid & 15;
    const int g = tid >> 4;        // 0..31

    float s = 0.f;
    #pragma unroll
    for (int m = 0; m < GRID / 32; ++m)        // 16 iterations
        s += partials[(size_t)(g + m * 32) * 16 + e];

    __shared__ float acc[32][17];
    acc[g][e] = s;
    __syncthreads();

    __shared__ float sums[16];
    if (tid < 16) {
        float t = 0.f;
        #pragma unroll
        for (int g2 = 0; g2 < 32; ++g2) t += acc[g2][tid];
        sums[tid] = t;
    }
    __syncthreads();
    if (tid == 0) {
        float loss = (float)NCLS;
        #pragma unroll
        for (int t = 0; t < NCLS; ++t) loss -= sums[t] / sums[NCLS + t];
        out[0] = loss;
    }
}

extern "C" void kernel_launch(void* const* d_in, const int* in_sizes, int n_in,
                              void* d_out, int out_size, void* d_ws, size_t ws_size,
                              hipStream_t stream) {
    const float* f = (const float*)d_in[0];   // patch, 8192 fp32
    const float* P = (const float*)d_in[1];   // prob, 8192x8 fp32
    // d_in[2] is k==8 (compile-time constant here)

    float* partials = (float*)d_ws;           // GRID*16 floats = 32 KB, fully overwritten

    sncut_rows<<<GRID, 256, 0, stream>>>(f, P, partials);
    sncut_final<<<1, 512, 0, stream>>>(partials, (float*)d_out);
}